// Round 5
// baseline (910.224 us; speedup 1.0000x reference)
//
#include <hip/hip_runtime.h>
#include <hip/hip_bf16.h>

// ============================================================================
// DIAGNOSTIC ROUND: kernels are bit-identical to round 4, but qkv is launched
// with 3x grid and attn with 8x grid (duplicate blocks recompute and write
// identical bytes -> deterministic, validation-safe). This makes each dispatch
// long enough (>232us) to displace the harness's 1.6GB fillBuffer dispatches
// from rocprof's top-5, giving per-kernel counters. dur_us ~= 3q + 8a.
// ============================================================================

typedef __attribute__((ext_vector_type(8))) short bf16x8;
typedef __attribute__((ext_vector_type(4))) float f32x4;

#define B_ 1024
#define T_ 256
#define C_ 384
#define H_ 64

static __device__ __forceinline__ unsigned short f2bf(float f) {
  unsigned int u = __float_as_uint(f);
  return (unsigned short)((u + 0x7fffu + ((u >> 16) & 1u)) >> 16);
}

static __device__ __forceinline__ void glds16(const void* g, void* l) {
  __builtin_amdgcn_global_load_lds((const __attribute__((address_space(1))) void*)g,
                                   (__attribute__((address_space(3))) void*)l, 16, 0, 0);
}

static __device__ __forceinline__ bf16x8 cvt8(float4 a, float4 b) {
  union { __hip_bfloat162 h[4]; bf16x8 v; } u;
  u.h[0] = __float22bfloat162_rn(make_float2(a.x, a.y));
  u.h[1] = __float22bfloat162_rn(make_float2(a.z, a.w));
  u.h[2] = __float22bfloat162_rn(make_float2(b.x, b.y));
  u.h[3] = __float22bfloat162_rn(make_float2(b.z, b.w));
  return u.v;
}

// wtp fragment-linear: wtp[((ks*12+nt)*64 + lane)*8 + i] =
//   bf16( W'[n = nt*16 + (lane&15)][k = ks*32 + (lane>>4)*8 + i] )
__global__ void pack_w_frag(const float* __restrict__ Wq, const float* __restrict__ Wk,
                            const float* __restrict__ Wv, unsigned short* __restrict__ wtp) {
  int id = blockIdx.x * 256 + threadIdx.x;
  if (id >= 144 * 512) return;
  int i = id & 7, lane = (id >> 3) & 63, f = id >> 9;
  int nt = f % 12, ks = f / 12;
  int n = nt * 16 + (lane & 15);
  int k = ks * 32 + (lane >> 4) * 8 + i;
  const float* W = (n < 64) ? Wq : ((n < 128) ? Wk : Wv);
  wtp[id] = f2bf(W[k * 64 + (n & 63)]);
}

// Q/K packed frag layout: qp[(((b*16+tile)*2+ks2)*64 + L)*8 + i] =
//   Q[b][tile*16 + (L&15)][ks2*32 + (L>>4)*8 + i]
// V packed frag (transposed): vp[(((b*4+nt)*8+ks)*64 + L)*8 + i] =
//   V[b][ks*32 + (L>>4)*8 + i][nt*16 + (L&15)]
__launch_bounds__(256, 2)
__global__ void qkv_kernel(const float* __restrict__ x, const float* __restrict__ cosp,
                           const float* __restrict__ sinp,
                           const unsigned short* __restrict__ wtp,
                           unsigned short* __restrict__ qp,
                           unsigned short* __restrict__ kp,
                           unsigned short* __restrict__ vp) {
  __shared__ __align__(16) char smem[4][8192];

  const int tid = threadIdx.x;
  const int w = tid >> 6;
  const int lane = tid & 63;
  const int l15 = lane & 15;
  const int lq = lane >> 4;
  const int bk = blockIdx.x & 2047;   // DIAG: grid = 3*2048, copies do identical work
  const int b = bk >> 1, half = bk & 1;
  const int tg0 = half * 8 + 2 * w;
  const int row0 = tg0 * 16;

  const float* xb = x + (size_t)b * T_ * C_;
  char* wbuf = smem[w];

  auto stage = [&](int ks, int hb) {
    char* dst = wbuf + hb * 4096;
    const int rl = lane >> 3;
    const int cg = lane & 7;
    #pragma unroll
    for (int s = 0; s < 4; ++s) {
      int row = s * 8 + rl;
      int cb = (cg * 16) ^ ((row & 7) << 4);
      const char* src = (const char*)(xb + (size_t)(row0 + row) * C_ + ks * 32) + cb;
      glds16(src, dst + s * 1024);
    }
  };

  f32x4 acc[2][12];
  #pragma unroll
  for (int i = 0; i < 2; ++i)
    #pragma unroll
    for (int nt = 0; nt < 12; ++nt) {
      f32x4 z = {0.f, 0.f, 0.f, 0.f};
      acc[i][nt] = z;
    }

  stage(0, 0);

  #pragma unroll
  for (int ks = 0; ks < 12; ++ks) {
    const int cur = ks & 1;
    asm volatile("s_waitcnt vmcnt(0)" ::: "memory");

    bf16x8 bfv[12];
    #pragma unroll
    for (int nt = 0; nt < 12; ++nt)
      bfv[nt] = *(const bf16x8*)(wtp + ((size_t)(ks * 12 + nt) * 64 + lane) * 8);

    if (ks + 1 < 12) stage(ks + 1, cur ^ 1);

    const char* cbuf = wbuf + cur * 4096;
    const int sw = (l15 & 7) << 4;
    bf16x8 af[2];
    #pragma unroll
    for (int i = 0; i < 2; ++i) {
      const char* rp = cbuf + (i * 16 + l15) * 128;
      float4 f0 = *(const float4*)(rp + ((lq * 32) ^ sw));
      float4 f1 = *(const float4*)(rp + ((lq * 32 + 16) ^ sw));
      af[i] = cvt8(f0, f1);
    }

    #pragma unroll
    for (int nt = 0; nt < 12; ++nt)
      #pragma unroll
      for (int i = 0; i < 2; ++i)
        acc[i][nt] = __builtin_amdgcn_mfma_f32_16x16x32_bf16(af[i], bfv[nt], acc[i][nt], 0, 0, 0);
  }

  // RoPE on q (nt 0..3) and k (nt 4..7)
  #pragma unroll
  for (int i = 0; i < 2; ++i) {
    #pragma unroll
    for (int j = 0; j < 4; ++j) {
      int t = (tg0 + i) * 16 + lq * 4 + j;
      #pragma unroll
      for (int h = 0; h < 2; ++h) {
        int c = h * 16 + l15;
        float cv = cosp[t * H_ + c];
        float sv = sinp[t * H_ + c];
        float a = acc[i][h][j], bb = acc[i][h + 2][j];
        acc[i][h][j]     = a * cv - bb * sv;
        acc[i][h + 2][j] = bb * cv + a * sv;
        float a2 = acc[i][4 + h][j], b2 = acc[i][6 + h][j];
        acc[i][4 + h][j] = a2 * cv - b2 * sv;
        acc[i][6 + h][j] = b2 * cv + a2 * sv;
      }
    }
  }

  // staged, fully-coalesced frag writeout (wave-local LDS reuse)
  unsigned short* st = (unsigned short*)wbuf;

  #pragma unroll
  for (int i = 0; i < 2; ++i)
    #pragma unroll
    for (int nt = 0; nt < 4; ++nt)
      #pragma unroll
      for (int j = 0; j < 4; ++j)
        st[i * 1152 + (lq * 4 + j) * 72 + nt * 16 + l15] = f2bf(acc[i][nt][j]);
  #pragma unroll
  for (int i = 0; i < 2; ++i)
    #pragma unroll
    for (int ks2 = 0; ks2 < 2; ++ks2) {
      bf16x8 fr = *(const bf16x8*)&st[i * 1152 + l15 * 72 + ks2 * 32 + lq * 8];
      *(bf16x8*)(qp + ((((size_t)b * 16 + tg0 + i) * 2 + ks2) * 64 + lane) * 8) = fr;
    }

  #pragma unroll
  for (int i = 0; i < 2; ++i)
    #pragma unroll
    for (int nt = 0; nt < 4; ++nt)
      #pragma unroll
      for (int j = 0; j < 4; ++j)
        st[i * 1152 + (lq * 4 + j) * 72 + nt * 16 + l15] = f2bf(acc[i][4 + nt][j]);
  #pragma unroll
  for (int i = 0; i < 2; ++i)
    #pragma unroll
    for (int ks2 = 0; ks2 < 2; ++ks2) {
      bf16x8 fr = *(const bf16x8*)&st[i * 1152 + l15 * 72 + ks2 * 32 + lq * 8];
      *(bf16x8*)(kp + ((((size_t)b * 16 + tg0 + i) * 2 + ks2) * 64 + lane) * 8) = fr;
    }

  #pragma unroll
  for (int i = 0; i < 2; ++i)
    #pragma unroll
    for (int nt = 0; nt < 4; ++nt)
      #pragma unroll
      for (int j = 0; j < 4; ++j)
        st[(nt * 16 + l15) * 40 + i * 16 + lq * 4 + j] = f2bf(acc[i][8 + nt][j]);
  {
    const int ksg = half * 4 + w;
    #pragma unroll
    for (int nt = 0; nt < 4; ++nt) {
      bf16x8 fr = *(const bf16x8*)&st[(nt * 16 + l15) * 40 + lq * 8];
      *(bf16x8*)(vp + ((((size_t)b * 4 + nt) * 8 + ksg) * 64 + lane) * 8) = fr;
    }
  }
}

__launch_bounds__(256, 4)
__global__ void attn_kernel(const unsigned short* __restrict__ qp,
                            const unsigned short* __restrict__ kp,
                            const unsigned short* __restrict__ vp,
                            float* __restrict__ out) {
  __shared__ unsigned short Plds[4 * 16 * 264];

  const int tid = threadIdx.x;
  const int w = tid >> 6;
  const int lane = tid & 63;
  const int l15 = lane & 15;
  const int lq = lane >> 4;
  const int bk = blockIdx.x & 2047;   // DIAG: grid = 8*2048, copies do identical work
  const int b = bk >> 1, half = bk & 1;
  const int rt2[2] = {half * 8 + w, half * 8 + 7 - w};

  unsigned short* Pw = Plds + w * 16 * 264;
  float* ob = out + (size_t)b * T_ * H_;

  #pragma unroll
  for (int i = 0; i < 2; ++i) {
    const int ti = rt2[i];
    const int t0 = ti * 16;

    bf16x8 aq[2];
    #pragma unroll
    for (int ks2 = 0; ks2 < 2; ++ks2)
      aq[ks2] = *(const bf16x8*)(qp + ((((size_t)b * 16 + ti) * 2 + ks2) * 64 + lane) * 8);

    f32x4 sacc[16];
    #pragma unroll
    for (int si = 0; si < 16; ++si) {
      f32x4 z = {0.f, 0.f, 0.f, 0.f};
      sacc[si] = z;
    }

    #pragma unroll
    for (int si = 0; si < 16; ++si) {
      if (si <= ti) {
        #pragma unroll
        for (int ks2 = 0; ks2 < 2; ++ks2) {
          bf16x8 bkf = *(const bf16x8*)(kp + ((((size_t)b * 16 + si) * 2 + ks2) * 64 + lane) * 8);
          sacc[si] = __builtin_amdgcn_mfma_f32_16x16x32_bf16(aq[ks2], bkf, sacc[si], 0, 0, 0);
        }
      }
    }

    int trow = t0 + lq * 4;
    #pragma unroll
    for (int si = 0; si < 16; ++si) {
      #pragma unroll
      for (int j = 0; j < 4; ++j) {
        float s = sacc[si][j] * 0.125f;
        if (si * 16 + l15 > trow + j) s = -1e30f;
        sacc[si][j] = s;
      }
    }

    float rl[4];
    #pragma unroll
    for (int j = 0; j < 4; ++j) {
      float mj = -1e30f;
      #pragma unroll
      for (int si = 0; si < 16; ++si) mj = fmaxf(mj, sacc[si][j]);
      #pragma unroll
      for (int d = 1; d < 16; d <<= 1) mj = fmaxf(mj, __shfl_xor(mj, d));
      float lj = 0.0f;
      #pragma unroll
      for (int si = 0; si < 16; ++si) {
        float p = __expf(sacc[si][j] - mj);
        lj += p;
        Pw[(lq * 4 + j) * 264 + si * 16 + l15] = f2bf(p);
      }
      #pragma unroll
      for (int d = 1; d < 16; d <<= 1) lj += __shfl_xor(lj, d);
      rl[j] = 1.0f / lj;
    }

    f32x4 oacc[4];
    #pragma unroll
    for (int nt = 0; nt < 4; ++nt) {
      f32x4 z = {0.f, 0.f, 0.f, 0.f};
      oacc[nt] = z;
    }
    int nk = (t0 + 16 + 31) >> 5;
    for (int ks = 0; ks < nk; ++ks) {
      bf16x8 ap = *(const bf16x8*)&Pw[l15 * 264 + ks * 32 + lq * 8];
      #pragma unroll
      for (int nt = 0; nt < 4; ++nt) {
        bf16x8 bv = *(const bf16x8*)(vp + ((((size_t)b * 4 + nt) * 8 + ks) * 64 + lane) * 8);
        oacc[nt] = __builtin_amdgcn_mfma_f32_16x16x32_bf16(ap, bv, oacc[nt], 0, 0, 0);
      }
    }

    #pragma unroll
    for (int nt = 0; nt < 4; ++nt)
      #pragma unroll
      for (int j = 0; j < 4; ++j)
        ob[(t0 + lq * 4 + j) * H_ + nt * 16 + l15] = oacc[nt][j] * rl[j];
  }
}

extern "C" void kernel_launch(void* const* d_in, const int* in_sizes, int n_in,
                              void* d_out, int out_size, void* d_ws, size_t ws_size,
                              hipStream_t stream) {
  const float* x    = (const float*)d_in[0];
  const float* cosp = (const float*)d_in[1];
  const float* sinp = (const float*)d_in[2];
  const float* Wq   = (const float*)d_in[3];
  const float* Wk   = (const float*)d_in[4];
  const float* Wv   = (const float*)d_in[5];
  float* out = (float*)d_out;

  const size_t wtp_bytes = 144 * 512 * 2;
  const size_t frag_elems = (size_t)B_ * 16 * 2 * 64 * 8;
  const size_t need = wtp_bytes + 3 * frag_elems * 2;

  unsigned short* wtp = (unsigned short*)d_ws;
  unsigned short* qp = (unsigned short*)((char*)d_ws + wtp_bytes);
  unsigned short* kp = qp + frag_elems;
  unsigned short* vp = kp + frag_elems;
  (void)need; (void)ws_size;

  pack_w_frag<<<288, 256, 0, stream>>>(Wq, Wk, Wv, wtp);
  // DIAGNOSTIC multiplied grids: qkv x3, attn x8 (identical redundant work)
  qkv_kernel<<<3 * 2048, 256, 0, stream>>>(x, cosp, sinp, wtp, qp, kp, vp);
  attn_kernel<<<8 * 2048, 256, 0, stream>>>(qp, kp, vp, out);
}

// Round 6
// 236.420 us; speedup vs baseline: 3.8500x; 3.8500x over previous
//
#include <hip/hip_runtime.h>
#include <hip/hip_bf16.h>

typedef __attribute__((ext_vector_type(8))) short bf16x8;
typedef __attribute__((ext_vector_type(4))) float f32x4;

#define B_ 1024
#define T_ 256
#define C_ 384
#define H_ 64

static __device__ __forceinline__ unsigned short f2bf(float f) {
  unsigned int u = __float_as_uint(f);
  return (unsigned short)((u + 0x7fffu + ((u >> 16) & 1u)) >> 16);
}

static __device__ __forceinline__ float bf2f(unsigned short h) {
  return __uint_as_float(((unsigned int)h) << 16);
}

static __device__ __forceinline__ bf16x8 cvt8(float4 a, float4 b) {
  union { __hip_bfloat162 h[4]; bf16x8 v; } u;
  u.h[0] = __float22bfloat162_rn(make_float2(a.x, a.y));
  u.h[1] = __float22bfloat162_rn(make_float2(a.z, a.w));
  u.h[2] = __float22bfloat162_rn(make_float2(b.x, b.y));
  u.h[3] = __float22bfloat162_rn(make_float2(b.z, b.w));
  return u.v;
}

// wtp fragment-linear: wtp[((ks*12+nt)*64 + lane)*8 + i] =
//   bf16( W'[n = nt*16 + (lane&15)][k = ks*32 + (lane>>4)*8 + i] )
__global__ void pack_w_frag(const float* __restrict__ Wq, const float* __restrict__ Wk,
                            const float* __restrict__ Wv, unsigned short* __restrict__ wtp) {
  int id = blockIdx.x * 256 + threadIdx.x;
  if (id >= 144 * 512) return;
  int i = id & 7, lane = (id >> 3) & 63, f = id >> 9;
  int nt = f % 12, ks = f / 12;
  int n = nt * 16 + (lane & 15);
  int k = ks * 32 + (lane >> 4) * 8 + i;
  const float* W = (n < 64) ? Wq : ((n < 128) ? Wk : Wv);
  wtp[id] = f2bf(W[k * 64 + (n & 63)]);
}

// Q/K packed frag layout: qp[(((b*16+tile)*2+ks2)*64 + L)*8 + i] =
//   Q[b][tile*16 + (L&15)][ks2*32 + (L>>4)*8 + i]   (RoPE applied)
// V packed frag (transposed): vp[(((b*4+nt)*8+ks)*64 + L)*8 + i] =
//   V[b][ks*32 + (L>>4)*8 + i][nt*16 + (L&15)]
//
// Block = 32 rows of one batch. Slab-staged GEMM: x slab -> LDS once (linear
// streaming), then the whole K=384 loop runs from LDS + L2-resident wtp.
__launch_bounds__(512, 4)
__global__ void qkv_kernel(const float* __restrict__ x, const float* __restrict__ cosp,
                           const float* __restrict__ sinp,
                           const unsigned short* __restrict__ wtp,
                           unsigned short* __restrict__ qp,
                           unsigned short* __restrict__ kp,
                           unsigned short* __restrict__ vp) {
  __shared__ __align__(16) unsigned short xs[32 * 384];   // bf16 slab, XOR-swizzled
  __shared__ __align__(16) unsigned short Qst[32 * 72];
  __shared__ __align__(16) unsigned short Kst[32 * 72];
  __shared__ __align__(16) unsigned short Vst[64 * 40];

  const int tid = threadIdx.x;
  const int w = tid >> 6;        // wave 0..7
  const int lane = tid & 63;
  const int l15 = lane & 15;
  const int lq = lane >> 4;
  const int bk = blockIdx.x;     // 0..8191
  const int b = bk >> 3, g32 = bk & 7;
  const int row0 = g32 * 32;

  const float* xb = x + (size_t)b * T_ * C_ + (size_t)row0 * C_;

  // ---- stage x slab: 1536 16B-bf16 chunks; thread t does chunks t, t+512, t+1024.
  // Global reads are 64-lane x 32B = 2KB contiguous per wave-instr (pure stream).
  #pragma unroll
  for (int s = 0; s < 3; ++s) {
    int c = s * 512 + tid;
    int row = c / 48;                 // 48 chunks per row
    int cb = (c - row * 48) * 16;     // byte offset within bf16 row
    const float* p = xb + c * 8;
    float4 f0 = *(const float4*)p;
    float4 f1 = *(const float4*)(p + 4);
    bf16x8 v = cvt8(f0, f1);
    *(bf16x8*)((char*)xs + row * 768 + (cb ^ ((row & 7) << 4))) = v;
  }
  __syncthreads();

  // ---- K-loop: wave = (row-tile rt, n-group ng of 3 n-tiles); all LDS + L2.
  const int rt = w & 1, ng = w >> 1;
  const int arow = rt * 16 + l15;
  const char* xrow = (const char*)xs + arow * 768;
  const int asw = (arow & 7) << 4;

  f32x4 acc[3];
  #pragma unroll
  for (int m = 0; m < 3; ++m) {
    f32x4 z = {0.f, 0.f, 0.f, 0.f};
    acc[m] = z;
  }

  #pragma unroll
  for (int ks = 0; ks < 12; ++ks) {
    bf16x8 af = *(const bf16x8*)(xrow + ((ks * 64 + lq * 16) ^ asw));
    #pragma unroll
    for (int m = 0; m < 3; ++m) {
      const int nt = ng * 3 + m;
      bf16x8 bv = *(const bf16x8*)(wtp + ((size_t)(ks * 12 + nt) * 64 + lane) * 8);
      acc[m] = __builtin_amdgcn_mfma_f32_16x16x32_bf16(af, bv, acc[m], 0, 0, 0);
    }
  }

  // ---- scatter-stage accumulators (raw, pre-RoPE) into staging tiles
  #pragma unroll
  for (int m = 0; m < 3; ++m) {
    const int nt = ng * 3 + m;
    #pragma unroll
    for (int j = 0; j < 4; ++j) {
      const int r32 = rt * 16 + lq * 4 + j;
      unsigned short v = f2bf(acc[m][j]);
      if (nt < 4)      Qst[r32 * 72 + nt * 16 + l15] = v;
      else if (nt < 8) Kst[r32 * 72 + (nt - 4) * 16 + l15] = v;
      else             Vst[((nt - 8) * 16 + l15) * 40 + r32] = v;
    }
  }
  __syncthreads();

  // ---- frag-line writeout (12 x 1KB lines), RoPE fused for Q/K lines
  #pragma unroll
  for (int pass = 0; pass < 2; ++pass) {
    const int id = pass * 8 + w;
    if (id < 12) {
      if (id < 8) {
        const unsigned short* S = (id < 4) ? Qst : Kst;
        unsigned short* dst = (id < 4) ? qp : kp;
        const int lid = id & 3;
        const int tl = lid >> 1;         // tile within block
        const int ks2 = lid & 1;
        const int r32 = tl * 16 + l15;   // row within 32-slab (lane L&15 = row)
        const int c0 = ks2 * 32 + lq * 8;
        const unsigned short* rowp = S + r32 * 72;
        bf16x8 mv = *(const bf16x8*)(rowp + c0);
        bf16x8 pv = *(const bf16x8*)(rowp + (c0 ^ 32));
        const int tglob = row0 + r32;
        const float* cp = cosp + tglob * H_ + c0;
        const float* sp = sinp + tglob * H_ + c0;
        float4 ca = *(const float4*)cp, cb = *(const float4*)(cp + 4);
        float4 sa = *(const float4*)sp, sb = *(const float4*)(sp + 4);
        const float sgn = ks2 ? 1.0f : -1.0f;
        bf16x8 ov;
        ov[0] = (short)f2bf(bf2f((unsigned short)mv[0]) * ca.x + sgn * bf2f((unsigned short)pv[0]) * sa.x);
        ov[1] = (short)f2bf(bf2f((unsigned short)mv[1]) * ca.y + sgn * bf2f((unsigned short)pv[1]) * sa.y);
        ov[2] = (short)f2bf(bf2f((unsigned short)mv[2]) * ca.z + sgn * bf2f((unsigned short)pv[2]) * sa.z);
        ov[3] = (short)f2bf(bf2f((unsigned short)mv[3]) * ca.w + sgn * bf2f((unsigned short)pv[3]) * sa.w);
        ov[4] = (short)f2bf(bf2f((unsigned short)mv[4]) * cb.x + sgn * bf2f((unsigned short)pv[4]) * sb.x);
        ov[5] = (short)f2bf(bf2f((unsigned short)mv[5]) * cb.y + sgn * bf2f((unsigned short)pv[5]) * sb.y);
        ov[6] = (short)f2bf(bf2f((unsigned short)mv[6]) * cb.z + sgn * bf2f((unsigned short)pv[6]) * sb.z);
        ov[7] = (short)f2bf(bf2f((unsigned short)mv[7]) * cb.w + sgn * bf2f((unsigned short)pv[7]) * sb.w);
        *(bf16x8*)(dst + ((((size_t)b * 16 + g32 * 2 + tl) * 2 + ks2) * 64 + lane) * 8) = ov;
      } else {
        const int ntv = id - 8;
        const int h = ntv * 16 + l15;
        bf16x8 fr = *(const bf16x8*)(Vst + h * 40 + lq * 8);
        *(bf16x8*)(vp + ((((size_t)b * 4 + ntv) * 8 + g32) * 64 + lane) * 8) = fr;
      }
    }
  }
}

__launch_bounds__(256, 4)
__global__ void attn_kernel(const unsigned short* __restrict__ qp,
                            const unsigned short* __restrict__ kp,
                            const unsigned short* __restrict__ vp,
                            float* __restrict__ out) {
  __shared__ unsigned short Plds[4 * 16 * 264];

  const int tid = threadIdx.x;
  const int w = tid >> 6;
  const int lane = tid & 63;
  const int l15 = lane & 15;
  const int lq = lane >> 4;
  const int bk = blockIdx.x;
  const int b = bk >> 1, half = bk & 1;
  const int rt2[2] = {half * 8 + w, half * 8 + 7 - w};

  unsigned short* Pw = Plds + w * 16 * 264;
  float* ob = out + (size_t)b * T_ * H_;

  #pragma unroll
  for (int i = 0; i < 2; ++i) {
    const int ti = rt2[i];
    const int t0 = ti * 16;

    bf16x8 aq[2];
    #pragma unroll
    for (int ks2 = 0; ks2 < 2; ++ks2)
      aq[ks2] = *(const bf16x8*)(qp + ((((size_t)b * 16 + ti) * 2 + ks2) * 64 + lane) * 8);

    f32x4 sacc[16];
    #pragma unroll
    for (int si = 0; si < 16; ++si) {
      f32x4 z = {0.f, 0.f, 0.f, 0.f};
      sacc[si] = z;
    }

    #pragma unroll
    for (int si = 0; si < 16; ++si) {
      if (si <= ti) {  // wave-uniform causal tile skip
        #pragma unroll
        for (int ks2 = 0; ks2 < 2; ++ks2) {
          bf16x8 bkf = *(const bf16x8*)(kp + ((((size_t)b * 16 + si) * 2 + ks2) * 64 + lane) * 8);
          sacc[si] = __builtin_amdgcn_mfma_f32_16x16x32_bf16(aq[ks2], bkf, sacc[si], 0, 0, 0);
        }
      }
    }

    int trow = t0 + lq * 4;
    #pragma unroll
    for (int si = 0; si < 16; ++si) {
      #pragma unroll
      for (int j = 0; j < 4; ++j) {
        float s = sacc[si][j] * 0.125f;
        if (si * 16 + l15 > trow + j) s = -1e30f;
        sacc[si][j] = s;
      }
    }

    float rl[4];
    #pragma unroll
    for (int j = 0; j < 4; ++j) {
      float mj = -1e30f;
      #pragma unroll
      for (int si = 0; si < 16; ++si) mj = fmaxf(mj, sacc[si][j]);
      #pragma unroll
      for (int d = 1; d < 16; d <<= 1) mj = fmaxf(mj, __shfl_xor(mj, d));
      float lj = 0.0f;
      #pragma unroll
      for (int si = 0; si < 16; ++si) {
        float p = __expf(sacc[si][j] - mj);
        lj += p;
        Pw[(lq * 4 + j) * 264 + si * 16 + l15] = f2bf(p);
      }
      #pragma unroll
      for (int d = 1; d < 16; d <<= 1) lj += __shfl_xor(lj, d);
      rl[j] = 1.0f / lj;
    }

    f32x4 oacc[4];
    #pragma unroll
    for (int nt = 0; nt < 4; ++nt) {
      f32x4 z = {0.f, 0.f, 0.f, 0.f};
      oacc[nt] = z;
    }
    int nk = (t0 + 16 + 31) >> 5;
    for (int ks = 0; ks < nk; ++ks) {
      bf16x8 ap = *(const bf16x8*)&Pw[l15 * 264 + ks * 32 + lq * 8];
      #pragma unroll
      for (int nt = 0; nt < 4; ++nt) {
        bf16x8 bv = *(const bf16x8*)(vp + ((((size_t)b * 4 + nt) * 8 + ks) * 64 + lane) * 8);
        oacc[nt] = __builtin_amdgcn_mfma_f32_16x16x32_bf16(ap, bv, oacc[nt], 0, 0, 0);
      }
    }

    #pragma unroll
    for (int nt = 0; nt < 4; ++nt)
      #pragma unroll
      for (int j = 0; j < 4; ++j)
        ob[(t0 + lq * 4 + j) * H_ + nt * 16 + l15] = oacc[nt][j] * rl[j];
  }
}

extern "C" void kernel_launch(void* const* d_in, const int* in_sizes, int n_in,
                              void* d_out, int out_size, void* d_ws, size_t ws_size,
                              hipStream_t stream) {
  const float* x    = (const float*)d_in[0];
  const float* cosp = (const float*)d_in[1];
  const float* sinp = (const float*)d_in[2];
  const float* Wq   = (const float*)d_in[3];
  const float* Wk   = (const float*)d_in[4];
  const float* Wv   = (const float*)d_in[5];
  float* out = (float*)d_out;

  const size_t wtp_bytes = 144 * 512 * 2;
  const size_t frag_elems = (size_t)B_ * 16 * 2 * 64 * 8;

  unsigned short* wtp = (unsigned short*)d_ws;
  unsigned short* qp = (unsigned short*)((char*)d_ws + wtp_bytes);
  unsigned short* kp = qp + frag_elems;
  unsigned short* vp = kp + frag_elems;
  (void)ws_size;

  pack_w_frag<<<288, 256, 0, stream>>>(Wq, Wk, Wv, wtp);
  qkv_kernel<<<B_ * 8, 512, 0, stream>>>(x, cosp, sinp, wtp, qp, kp, vp);
  attn_kernel<<<B_ * 2, 256, 0, stream>>>(qp, kp, vp, out);
}